// Round 16
// baseline (66.971 us; speedup 1.0000x reference)
//
#include <hip/hip_runtime.h>

#define BB 8
#define CC 256
#define NN 4096
#define DD 32
#define NK 1024

typedef unsigned short u16;
typedef unsigned int   u32;
typedef __attribute__((ext_vector_type(8))) short bf16x8;
typedef __attribute__((ext_vector_type(4))) float f32x4;

#define MFMA16 __builtin_amdgcn_mfma_f32_16x16x32_bf16

// workspace offsets (in floats) — total 1,744,896 f = 7.0 MB
#define OFF_WVO  0u          // [CC][CC] bf16                 32,768 f
#define OFF_WQB  32768u      // (unused)                       4,096 f
#define OFF_WKB  36864u      // [DD][CC] bf16                  4,096 f
#define OFF_QF   40960u      // qF  [B][256 n16][64][8]      524,288 f
#define OFF_KF   565248u     // kF  [B][64 m16][64][8]       131,072 f
#define OFF_VOF  696320u     // voF [B][32 m32][16 o16][64][8] 1,048,576 f

__device__ __forceinline__ u16 f2bf(float f) {
    u32 u = __float_as_uint(f);
    u += 0x7FFFu + ((u >> 16) & 1u);      // RNE
    return (u16)(u >> 16);
}

__device__ __forceinline__ u32 cvt_pk_bf16(float lo, float hi) {
    u32 r;
    asm("v_cvt_pk_bf16_f32 %0, %1, %2" : "=v"(r) : "v"(lo), "v"(hi));
    return r;
}

// ==== kernel1: q-projection (blocks 0..255, wq converted inline) ============
// ==== + wvo = wo@wv GEMM rows (blocks 256..511) + wk conversion =============
__launch_bounds__(256)
__global__ void qwv_kernel(const float* __restrict__ x,  const float* __restrict__ wq,
                           const float* __restrict__ wk, const float* __restrict__ wv,
                           const float* __restrict__ wo,
                           u16* __restrict__ qF, u16* __restrict__ wkb,
                           u16* __restrict__ wvob) {
    int t = threadIdx.x;
    const float QS = 0.17677669529663687f * 1.4426950408889634f; // 1/sqrt(32)*log2e

    if (blockIdx.x >= 256) {
        // ---------------- wvo GEMM row obk + wk conversion -------------------
        int obk = blockIdx.x - 256, c = t;
        const float* wop = wo + obk * CC;
        float acc = 0.f;
#pragma unroll 8
        for (int j = 0; j < CC; ++j)
            acc += wop[j] * wv[(size_t)j * CC + c];   // wop: wave-uniform s_load
        wvob[obk * CC + c] = f2bf(acc);
        if (obk < DD)
            wkb[obk * CC + c] = f2bf(wk[obk * CC + c]);
        return;
    }

    // ---------------- Q path (identical to R13 except inline wq) -------------
    __shared__ float xl[64 * 136];               // [c64][n128 pad136] 34.8 KB
    int w = t >> 6, l = t & 63, l15 = l & 15, lg = l >> 4;
    int b = blockIdx.x & 7, nb = blockIdx.x >> 3;
    int n0 = nb * 128;
    const f32x4 fz = {0.f, 0.f, 0.f, 0.f};
    f32x4 acc[2][2];
    acc[0][0] = fz; acc[0][1] = fz; acc[1][0] = fz; acc[1][1] = fz;
    int cr = t >> 2, seg = (t & 3) * 32;
    for (int ch = 0; ch < 4; ++ch) {
        int c0 = ch * 64;
        const float* xs = x + ((size_t)(b * CC + c0 + cr)) * NN + n0 + seg;
#pragma unroll
        for (int p = 0; p < 8; ++p)
            *(float4*)&xl[cr * 136 + seg + p * 4] = *(const float4*)(xs + p * 4);
        __syncthreads();
#pragma unroll
        for (int ks = 0; ks < 2; ++ks) {
            int klo = ks * 32 + lg * 8;          // c-local base of this frag
            // inline wq fragments for both d-tiles (hoisted out of i-loop)
            union { u32 u[4]; bf16x8 v; } bq[2];
#pragma unroll
            for (int dt = 0; dt < 2; ++dt) {
                const float* wqr = wq + (size_t)(dt * 16 + l15) * CC + c0 + klo;
                float4 a4 = *(const float4*)wqr;
                float4 b4 = *(const float4*)(wqr + 4);
                bq[dt].u[0] = cvt_pk_bf16(a4.x * QS, a4.y * QS);
                bq[dt].u[1] = cvt_pk_bf16(a4.z * QS, a4.w * QS);
                bq[dt].u[2] = cvt_pk_bf16(b4.x * QS, b4.y * QS);
                bq[dt].u[3] = cvt_pk_bf16(b4.z * QS, b4.w * QS);
            }
#pragma unroll
            for (int i = 0; i < 2; ++i) {
                int nl = w * 32 + i * 16 + l15;
                float f0 = xl[(klo + 0) * 136 + nl];
                float f1 = xl[(klo + 1) * 136 + nl];
                float f2 = xl[(klo + 2) * 136 + nl];
                float f3 = xl[(klo + 3) * 136 + nl];
                float f4 = xl[(klo + 4) * 136 + nl];
                float f5 = xl[(klo + 5) * 136 + nl];
                float f6 = xl[(klo + 6) * 136 + nl];
                float f7 = xl[(klo + 7) * 136 + nl];
                union { u32 u[4]; bf16x8 v; } cv;
                cv.u[0] = cvt_pk_bf16(f0, f1);
                cv.u[1] = cvt_pk_bf16(f2, f3);
                cv.u[2] = cvt_pk_bf16(f4, f5);
                cv.u[3] = cvt_pk_bf16(f6, f7);
#pragma unroll
                for (int dt = 0; dt < 2; ++dt)
                    acc[i][dt] = MFMA16(cv.v, bq[dt].v, acc[i][dt], 0, 0, 0);
            }
        }
        __syncthreads();
    }
    // scatter qF packed: tile = nb*8 + w*2 + i
    u16* outp = qF + (size_t)b * 256 * 512;
#pragma unroll
    for (int i = 0; i < 2; ++i)
#pragma unroll
        for (int dt = 0; dt < 2; ++dt)
#pragma unroll
            for (int r2 = 0; r2 < 4; ++r2) {
                int tile = nb * 8 + w * 2 + i;
                int dhi = dt * 2 + (l15 >> 3);
                outp[((size_t)tile * 64 + dhi * 16 + lg * 4 + r2) * 8 + (l15 & 7)]
                    = f2bf(acc[i][dt][r2]);
            }
}

// ==== kernel2: k + vo projection (pool-on-the-fly, reg-staged prefetch) =====
// block = (b, hk): pooled row hk (32 m). grid = 256.
__launch_bounds__(256)
__global__ void kv_kernel(const float* __restrict__ x,
                          const u16* __restrict__ wkb, const u16* __restrict__ wvob,
                          u16* __restrict__ kF, u16* __restrict__ voF) {
    __shared__ u16 pl[64 * 42];                  // pooled bf16 [c64][m32 pad42]
    int t = threadIdx.x, w = t >> 6, l = t & 63, l15 = l & 15, lg = l >> 4;
    const f32x4 fz = {0.f, 0.f, 0.f, 0.f};
    int b = blockIdx.x & 7, hk = blockIdx.x >> 3;
    f32x4 acck = fz;
    f32x4 accv[2][4];
#pragma unroll
    for (int mt = 0; mt < 2; ++mt)
#pragma unroll
        for (int ot = 0; ot < 4; ++ot) accv[mt][ot] = fz;

    int cr = t >> 2, w8 = (t & 3) * 8;
    const float* xbase = x + ((size_t)(b * CC + cr)) * NN + (2 * hk) * 64 + w8 * 2;

    // prefetch chunk 0
    float4 xr[8], xn[8];
    {
        const float* xs = xbase;
        xr[0] = *(const float4*)(xs +  0); xr[1] = *(const float4*)(xs +  4);
        xr[2] = *(const float4*)(xs +  8); xr[3] = *(const float4*)(xs + 12);
        xr[4] = *(const float4*)(xs + 64); xr[5] = *(const float4*)(xs + 68);
        xr[6] = *(const float4*)(xs + 72); xr[7] = *(const float4*)(xs + 76);
    }

    for (int ch = 0; ch < 4; ++ch) {
        int c0 = ch * 64;
        // issue next-chunk loads (latency hidden under pool+MFMA below)
        if (ch < 3) {
            const float* xs = xbase + (size_t)(c0 + 64) * NN;
            xn[0] = *(const float4*)(xs +  0); xn[1] = *(const float4*)(xs +  4);
            xn[2] = *(const float4*)(xs +  8); xn[3] = *(const float4*)(xs + 12);
            xn[4] = *(const float4*)(xs + 64); xn[5] = *(const float4*)(xs + 68);
            xn[6] = *(const float4*)(xs + 72); xn[7] = *(const float4*)(xs + 76);
        }
        // pool 2x2 from registers
        {
            float p0 = 0.25f * (xr[0].x + xr[0].y + xr[4].x + xr[4].y);
            float p1 = 0.25f * (xr[0].z + xr[0].w + xr[4].z + xr[4].w);
            float p2 = 0.25f * (xr[1].x + xr[1].y + xr[5].x + xr[5].y);
            float p3 = 0.25f * (xr[1].z + xr[1].w + xr[5].z + xr[5].w);
            float p4 = 0.25f * (xr[2].x + xr[2].y + xr[6].x + xr[6].y);
            float p5 = 0.25f * (xr[2].z + xr[2].w + xr[6].z + xr[6].w);
            float p6 = 0.25f * (xr[3].x + xr[3].y + xr[7].x + xr[7].y);
            float p7 = 0.25f * (xr[3].z + xr[3].w + xr[7].z + xr[7].w);
            u32* pw = (u32*)&pl[cr * 42 + w8];
            pw[0] = cvt_pk_bf16(p0, p1);
            pw[1] = cvt_pk_bf16(p2, p3);
            pw[2] = cvt_pk_bf16(p4, p5);
            pw[3] = cvt_pk_bf16(p6, p7);
        }
        __syncthreads();
#pragma unroll
        for (int ks = 0; ks < 2; ++ks) {
            int klo = ks * 32 + lg * 8;
            bf16x8 pm[2];
#pragma unroll
            for (int mt = 0; mt < 2; ++mt) {
                union { u16 s[8]; bf16x8 v; } cv;
#pragma unroll
                for (int j = 0; j < 8; ++j)
                    cv.s[j] = pl[(klo + j) * 42 + mt * 16 + l15];
                pm[mt] = cv.v;
            }
            {
                bf16x8 bk = *(const bf16x8*)(wkb + (size_t)((w & 1) * 16 + l15) * CC + c0 + klo);
                acck = MFMA16(pm[w >> 1], bk, acck, 0, 0, 0);
            }
#pragma unroll
            for (int ot = 0; ot < 4; ++ot) {
                bf16x8 ao = *(const bf16x8*)(wvob + (size_t)(w * 64 + ot * 16 + l15) * CC + c0 + klo);
#pragma unroll
                for (int mt = 0; mt < 2; ++mt)
                    accv[mt][ot] = MFMA16(ao, pm[mt], accv[mt][ot], 0, 0, 0);
            }
        }
        __syncthreads();
#pragma unroll
        for (int p = 0; p < 8; ++p) xr[p] = xn[p];
    }
#pragma unroll
    for (int r2 = 0; r2 < 4; ++r2)
        kF[((size_t)(b * 64 + hk * 2 + (w >> 1)) * 64
            + ((w & 1) * 2 + (l15 >> 3)) * 16 + lg * 4 + r2) * 8 + (l15 & 7)]
            = f2bf(acck[r2]);
#pragma unroll
    for (int mt = 0; mt < 2; ++mt)
#pragma unroll
        for (int ot = 0; ot < 4; ++ot)
#pragma unroll
            for (int r2 = 0; r2 < 4; ++r2)
                voF[(((size_t)(b * 32 + hk) * 16 + w * 4 + ot) * 64
                     + (mt * 2 + (l15 >> 3)) * 16 + lg * 4 + r2) * 8 + (l15 & 7)]
                    = f2bf(accv[mt][ot][r2]);
}

// ==== fused flash attention (MFMA) + epilogue — R13 best, unchanged =========
__launch_bounds__(256, 2)
__global__ void attn_kernel(const u16* __restrict__ qF, const u16* __restrict__ kF,
                            const u16* __restrict__ voF, const float* __restrict__ x,
                            const float* __restrict__ gamma, float* __restrict__ out) {
    __shared__ __align__(16) u16   p_lds[2][64 * 40];   // [buf][n][m] 10 KB
    __shared__ __align__(16) float rs_lds[64];

    const int t   = threadIdx.x;
    const int w   = t >> 6, l = t & 63;
    const int l15 = l & 15, lg = l >> 4;
    const int b   = blockIdx.x & 7;              // batch -> XCD pin
    const int n0  = (blockIdx.x >> 3) << 6;      // 64-row tile

    bf16x8 qf = *(const bf16x8*)(qF + ((size_t)(b * 256 + (n0 >> 4) + w) * 64 + l) * 8);
    const u16* kfp = kF  + ((size_t)(b * 64) * 64 + l) * 8;                 // + m16*512
    const u16* vbl = voF + ((size_t)((b * 32) * 16 + w * 4) * 64 + l) * 8;  // + i*8192 + of*512

    u16*       pwp = &p_lds[0][(w * 16 + l15) * 40 + lg * 4];
    const u16* prp = &p_lds[0][l15 * 40 + lg * 8];

    f32x4 acc[4][4];
    const f32x4 fz = {0.f, 0.f, 0.f, 0.f};
#pragma unroll
    for (int j = 0; j < 4; ++j)
#pragma unroll
        for (int of = 0; of < 4; ++of) acc[j][of] = fz;
    float rs = 0.f;

    // ---- prologue: P(0) -> buf0; K frags for QK(1); VO(0) + VO(1) issued ---
    bf16x8 kf0 = *(const bf16x8*)(kfp);
    bf16x8 kf1 = *(const bf16x8*)(kfp + 512);
    {
        f32x4 c0 = MFMA16(kf0, qf, fz, 0, 0, 0);
        f32x4 c1 = MFMA16(kf1, qf, fz, 0, 0, 0);
        float e0 = __builtin_amdgcn_exp2f(c0[0]);
        float e1 = __builtin_amdgcn_exp2f(c0[1]);
        float e2 = __builtin_amdgcn_exp2f(c0[2]);
        float e3 = __builtin_amdgcn_exp2f(c0[3]);
        float e4 = __builtin_amdgcn_exp2f(c1[0]);
        float e5 = __builtin_amdgcn_exp2f(c1[1]);
        float e6 = __builtin_amdgcn_exp2f(c1[2]);
        float e7 = __builtin_amdgcn_exp2f(c1[3]);
        rs += (e0 + e1 + e2 + e3) + (e4 + e5 + e6 + e7);
        uint2 pw0, pw1;
        pw0.x = cvt_pk_bf16(e0, e1);
        pw0.y = cvt_pk_bf16(e2, e3);
        pw1.x = cvt_pk_bf16(e4, e5);
        pw1.y = cvt_pk_bf16(e6, e7);
        *(uint2*)pwp        = pw0;
        *(uint2*)(pwp + 16) = pw1;
    }
    kf0 = *(const bf16x8*)(kfp + 2 * 512);
    kf1 = *(const bf16x8*)(kfp + 3 * 512);
    bf16x8 vof0[4], vof1[4];
#pragma unroll
    for (int of = 0; of < 4; ++of)
        vof0[of] = *(const bf16x8*)(vbl + of * 512);
#pragma unroll
    for (int of = 0; of < 4; ++of)
        vof1[of] = *(const bf16x8*)(vbl + 8192 + of * 512);
    asm volatile("s_waitcnt lgkmcnt(0)" ::: "memory");
    __builtin_amdgcn_s_barrier();

    // ---- steady state: i = 0..30, fully unconditional body ------------------
#pragma unroll 2
    for (int i = 0; i < 31; ++i) {
        const int buf = i & 1;
        // VO(i+2) prefetch (clamped; ~2 iters of latency cover)
        const int ip2 = (i + 2 > 31) ? 31 : (i + 2);
        bf16x8 vof2[4];
#pragma unroll
        for (int of = 0; of < 4; ++of)
            vof2[of] = *(const bf16x8*)(vbl + (size_t)ip2 * 8192 + of * 512);
        // QK(i+1) + P-write into buf^1
        {
            f32x4 c0 = MFMA16(kf0, qf, fz, 0, 0, 0);
            f32x4 c1 = MFMA16(kf1, qf, fz, 0, 0, 0);
            const int k0i = (2 * i + 4 > 62) ? 62 : (2 * i + 4);   // clamped K prefetch
            kf0 = *(const bf16x8*)(kfp + (size_t)k0i * 512);
            kf1 = *(const bf16x8*)(kfp + (size_t)(k0i + 1) * 512);
            float e0 = __builtin_amdgcn_exp2f(c0[0]);
            float e1 = __builtin_amdgcn_exp2f(c0[1]);
            float e2 = __builtin_amdgcn_exp2f(c0[2]);
            float e3 = __builtin_amdgcn_exp2f(c0[3]);
            float e4 = __builtin_amdgcn_exp2f(c1[0]);
            float e5 = __builtin_amdgcn_exp2f(c1[1]);
            float e6 = __builtin_amdgcn_exp2f(c1[2]);
            float e7 = __builtin_amdgcn_exp2f(c1[3]);
            rs += (e0 + e1 + e2 + e3) + (e4 + e5 + e6 + e7);
            uint2 pw0, pw1;
            pw0.x = cvt_pk_bf16(e0, e1);
            pw0.y = cvt_pk_bf16(e2, e3);
            pw1.x = cvt_pk_bf16(e4, e5);
            pw1.y = cvt_pk_bf16(e6, e7);
            u16* pw = pwp + (buf ^ 1) * 2560;
            *(uint2*)pw        = pw0;
            *(uint2*)(pw + 16) = pw1;
        }
        // PV(i) with vof0 (loaded 2 iters ago — resident)
        const u16* pr = prp + buf * 2560;
        __builtin_amdgcn_s_setprio(1);
#pragma unroll
        for (int j = 0; j < 4; ++j) {
            bf16x8 pa = *(const bf16x8*)(pr + j * 640);
#pragma unroll
            for (int of = 0; of < 4; ++of)
                acc[j][of] = MFMA16(pa, vof0[of], acc[j][of], 0, 0, 0);
        }
        __builtin_amdgcn_s_setprio(0);
        // single barrier: LDS drain only; global loads stay in flight
        asm volatile("s_waitcnt lgkmcnt(0)" ::: "memory");
        __builtin_amdgcn_s_barrier();
        // rotate pipelines
#pragma unroll
        for (int of = 0; of < 4; ++of) { vof0[of] = vof1[of]; vof1[of] = vof2[of]; }
    }

    // ---- tail: PV(31) from buf1 ---------------------------------------------
    {
        const u16* pr = prp + 2560;
#pragma unroll
        for (int j = 0; j < 4; ++j) {
            bf16x8 pa = *(const bf16x8*)(pr + j * 640);
#pragma unroll
            for (int of = 0; of < 4; ++of)
                acc[j][of] = MFMA16(pa, vof0[of], acc[j][of], 0, 0, 0);
        }
    }

    // ---- row sums (full m per wave) -----------------------------------------
    rs += __shfl_xor(rs, 16);
    rs += __shfl_xor(rs, 32);
    if (l < 16) rs_lds[w * 16 + l] = rs;
    __syncthreads();

    // ---- epilogue (all 4 waves): out[b][o][n] = x + g * O / rs --------------
    float g = gamma[0];
#pragma unroll
    for (int j = 0; j < 4; ++j) {
        int rbase = j * 16 + lg * 4;
        float fa0 = g / rs_lds[rbase + 0];
        float fa1 = g / rs_lds[rbase + 1];
        float fa2 = g / rs_lds[rbase + 2];
        float fa3 = g / rs_lds[rbase + 3];
#pragma unroll
        for (int of = 0; of < 4; ++of) {
            size_t base = ((size_t)(b * CC + w * 64 + of * 16 + l15)) * NN
                        + n0 + j * 16 + lg * 4;
            float4 xv = *(const float4*)(x + base);
            float4 ov;
            ov.x = xv.x + acc[j][of][0] * fa0;
            ov.y = xv.y + acc[j][of][1] * fa1;
            ov.z = xv.z + acc[j][of][2] * fa2;
            ov.w = xv.w + acc[j][of][3] * fa3;
            *(float4*)(out + base) = ov;
        }
    }
}

extern "C" void kernel_launch(void* const* d_in, const int* in_sizes, int n_in,
                              void* d_out, int out_size, void* d_ws, size_t ws_size,
                              hipStream_t stream) {
    const float* x     = (const float*)d_in[0];
    const float* wq    = (const float*)d_in[1];
    const float* wk    = (const float*)d_in[2];
    const float* wv    = (const float*)d_in[3];
    const float* wo    = (const float*)d_in[4];
    const float* gamma = (const float*)d_in[5];
    float* out = (float*)d_out;
    float* ws  = (float*)d_ws;

    u16* wvob = (u16*)(ws + OFF_WVO);
    u16* wkb  = (u16*)(ws + OFF_WKB);
    u16* qF   = (u16*)(ws + OFF_QF);
    u16* kF   = (u16*)(ws + OFF_KF);
    u16* voF  = (u16*)(ws + OFF_VOF);

    qwv_kernel <<<dim3(512), dim3(256), 0, stream>>>(x, wq, wk, wv, wo, qF, wkb, wvob);
    kv_kernel  <<<dim3(256), dim3(256), 0, stream>>>(x, wkb, wvob, kF, voF);
    attn_kernel<<<dim3(512), dim3(256), 0, stream>>>(qF, kF, voF, x, gamma, out);
}

// Round 17
// 57.386 us; speedup vs baseline: 1.1670x; 1.1670x over previous
//
#include <hip/hip_runtime.h>

#define BB 8
#define CC 256
#define NN 4096
#define DD 32
#define NK 1024

typedef unsigned short u16;
typedef unsigned int   u32;
typedef __attribute__((ext_vector_type(8))) short bf16x8;
typedef __attribute__((ext_vector_type(4))) float f32x4;

#define MFMA16 __builtin_amdgcn_mfma_f32_16x16x32_bf16

// workspace offsets (in floats) — total 1,744,896 f = 7.0 MB
#define OFF_WVO  0u          // [CC][CC] bf16                 32,768 f
#define OFF_WQB  32768u      // [DD][CC] bf16                  4,096 f
#define OFF_WKB  36864u      // [DD][CC] bf16                  4,096 f
#define OFF_QF   40960u      // qF  [B][256 n16][64][8]      524,288 f
#define OFF_KF   565248u     // kF  [B][64 m16][64][8]       131,072 f
#define OFF_VOF  696320u     // voF [B][32 m32][16 o16][64][8] 1,048,576 f

__device__ __forceinline__ u16 f2bf(float f) {
    u32 u = __float_as_uint(f);
    u += 0x7FFFu + ((u >> 16) & 1u);      // RNE
    return (u16)(u >> 16);
}

__device__ __forceinline__ u32 cvt_pk_bf16(float lo, float hi) {
    u32 r;
    asm("v_cvt_pk_bf16_f32 %0, %1, %2" : "=v"(r) : "v"(lo), "v"(hi));
    return r;
}

// ==== weight prep: wvo = wo@wv (4-way split k + LDS reduce) + bf16 convs ====
__launch_bounds__(1024)
__global__ void wprep_kernel(const float* __restrict__ wq, const float* __restrict__ wk,
                             const float* __restrict__ wv, const float* __restrict__ wo,
                             u16* __restrict__ wqb, u16* __restrict__ wkb,
                             u16* __restrict__ wvob) {
    __shared__ float part[4][256];
    int o = blockIdx.x, t = threadIdx.x;
    int jq = t >> 8, c = t & 255;
    const float* wvp = wv + (size_t)(jq * 64) * CC + c;
    const float* wop = wo + o * CC + jq * 64;
    float acc = 0.f;
#pragma unroll 8
    for (int i = 0; i < 64; ++i)
        acc += wop[i] * wvp[(size_t)i * CC];
    part[jq][c] = acc;
    __syncthreads();
    if (t < 256)
        wvob[o * CC + t] = f2bf(part[0][t] + part[1][t] + part[2][t] + part[3][t]);
    if (o < 8) {
        const float QS = 0.17677669529663687f * 1.4426950408889634f; // 1/sqrt(32)*log2e
        int id = o * 1024 + t;
        wqb[id] = f2bf(wq[id] * QS);
    } else if (o < 16) {
        int id = (o - 8) * 1024 + t;
        wkb[id] = f2bf(wk[id]);
    }
}

// ==== projections directly from x (no intermediates) ========================
// blocks [0,256):  q-path.  b=blk&7, 128-n tile; LDS-staged transpose.
// blocks [256,512): k+vo.   b=blk2&7, pooled row hk (32 m); pool-on-the-fly.
__launch_bounds__(256)
__global__ void proj_kernel(const float* __restrict__ x,
                            const u16* __restrict__ wqb, const u16* __restrict__ wkb,
                            const u16* __restrict__ wvob,
                            u16* __restrict__ qF, u16* __restrict__ kF,
                            u16* __restrict__ voF) {
    int t = threadIdx.x, w = t >> 6, l = t & 63, l15 = l & 15, lg = l >> 4;
    const f32x4 fz = {0.f, 0.f, 0.f, 0.f};

    if (blockIdx.x < 256) {
        // ------------------- Q path -------------------
        __shared__ float xl[64 * 136];               // [c64][n128 pad136] 34.8 KB
        int b = blockIdx.x & 7, nb = blockIdx.x >> 3;
        int n0 = nb * 128;
        f32x4 acc[2][2];
        acc[0][0] = fz; acc[0][1] = fz; acc[1][0] = fz; acc[1][1] = fz;
        int cr = t >> 2, seg = (t & 3) * 32;
        for (int ch = 0; ch < 4; ++ch) {
            int c0 = ch * 64;
            const float* xs = x + ((size_t)(b * CC + c0 + cr)) * NN + n0 + seg;
#pragma unroll
            for (int p = 0; p < 8; ++p)
                *(float4*)&xl[cr * 136 + seg + p * 4] = *(const float4*)(xs + p * 4);
            __syncthreads();
#pragma unroll
            for (int ks = 0; ks < 2; ++ks) {
                int klo = ks * 32 + lg * 8;          // c-local base of this frag
#pragma unroll
                for (int i = 0; i < 2; ++i) {
                    int nl = w * 32 + i * 16 + l15;
                    float f0 = xl[(klo + 0) * 136 + nl];
                    float f1 = xl[(klo + 1) * 136 + nl];
                    float f2 = xl[(klo + 2) * 136 + nl];
                    float f3 = xl[(klo + 3) * 136 + nl];
                    float f4 = xl[(klo + 4) * 136 + nl];
                    float f5 = xl[(klo + 5) * 136 + nl];
                    float f6 = xl[(klo + 6) * 136 + nl];
                    float f7 = xl[(klo + 7) * 136 + nl];
                    union { u32 u[4]; bf16x8 v; } cv;
                    cv.u[0] = cvt_pk_bf16(f0, f1);
                    cv.u[1] = cvt_pk_bf16(f2, f3);
                    cv.u[2] = cvt_pk_bf16(f4, f5);
                    cv.u[3] = cvt_pk_bf16(f6, f7);
#pragma unroll
                    for (int dt = 0; dt < 2; ++dt) {
                        bf16x8 bq = *(const bf16x8*)(wqb + (size_t)(dt * 16 + l15) * CC + c0 + klo);
                        acc[i][dt] = MFMA16(cv.v, bq, acc[i][dt], 0, 0, 0);
                    }
                }
            }
            __syncthreads();
        }
        // scatter qF packed: tile = nb*8 + w*2 + i
        u16* outp = qF + (size_t)b * 256 * 512;
#pragma unroll
        for (int i = 0; i < 2; ++i)
#pragma unroll
            for (int dt = 0; dt < 2; ++dt)
#pragma unroll
                for (int r2 = 0; r2 < 4; ++r2) {
                    int tile = nb * 8 + w * 2 + i;
                    int dhi = dt * 2 + (l15 >> 3);
                    outp[((size_t)tile * 64 + dhi * 16 + lg * 4 + r2) * 8 + (l15 & 7)]
                        = f2bf(acc[i][dt][r2]);
                }
    } else {
        // ------------------- K + VO path -------------------
        __shared__ u16 pl[64 * 42];                  // pooled bf16 [c64][m32 pad42]
        int blk2 = blockIdx.x - 256;
        int b = blk2 & 7, hk = blk2 >> 3;            // pooled row hk, m0 = hk*32
        f32x4 acck = fz;
        f32x4 accv[2][4];
#pragma unroll
        for (int mt = 0; mt < 2; ++mt)
#pragma unroll
            for (int ot = 0; ot < 4; ++ot) accv[mt][ot] = fz;

        int cr = t >> 2, w8 = (t & 3) * 8;
        for (int ch = 0; ch < 4; ++ch) {
            int c0 = ch * 64;
            const float* xs = x + ((size_t)(b * CC + c0 + cr)) * NN + (2 * hk) * 64 + w8 * 2;
            float4 A0 = *(const float4*)(xs +  0), A1 = *(const float4*)(xs +  4);
            float4 A2 = *(const float4*)(xs +  8), A3 = *(const float4*)(xs + 12);
            float4 B0 = *(const float4*)(xs + 64), B1 = *(const float4*)(xs + 68);
            float4 B2 = *(const float4*)(xs + 72), B3 = *(const float4*)(xs + 76);
            float p0 = 0.25f * (A0.x + A0.y + B0.x + B0.y);
            float p1 = 0.25f * (A0.z + A0.w + B0.z + B0.w);
            float p2 = 0.25f * (A1.x + A1.y + B1.x + B1.y);
            float p3 = 0.25f * (A1.z + A1.w + B1.z + B1.w);
            float p4 = 0.25f * (A2.x + A2.y + B2.x + B2.y);
            float p5 = 0.25f * (A2.z + A2.w + B2.z + B2.w);
            float p6 = 0.25f * (A3.x + A3.y + B3.x + B3.y);
            float p7 = 0.25f * (A3.z + A3.w + B3.z + B3.w);
            u32* pw = (u32*)&pl[cr * 42 + w8];
            pw[0] = cvt_pk_bf16(p0, p1);
            pw[1] = cvt_pk_bf16(p2, p3);
            pw[2] = cvt_pk_bf16(p4, p5);
            pw[3] = cvt_pk_bf16(p6, p7);
            __syncthreads();
#pragma unroll
            for (int ks = 0; ks < 2; ++ks) {
                int klo = ks * 32 + lg * 8;
                bf16x8 pm[2];
#pragma unroll
                for (int mt = 0; mt < 2; ++mt) {
                    union { u16 s[8]; bf16x8 v; } cv;
#pragma unroll
                    for (int j = 0; j < 8; ++j)
                        cv.s[j] = pl[(klo + j) * 42 + mt * 16 + l15];
                    pm[mt] = cv.v;
                }
                {
                    bf16x8 bk = *(const bf16x8*)(wkb + (size_t)((w & 1) * 16 + l15) * CC + c0 + klo);
                    acck = MFMA16(pm[w >> 1], bk, acck, 0, 0, 0);
                }
#pragma unroll
                for (int ot = 0; ot < 4; ++ot) {
                    bf16x8 ao = *(const bf16x8*)(wvob + (size_t)(w * 64 + ot * 16 + l15) * CC + c0 + klo);
#pragma unroll
                    for (int mt = 0; mt < 2; ++mt)
                        accv[mt][ot] = MFMA16(ao, pm[mt], accv[mt][ot], 0, 0, 0);
                }
            }
            __syncthreads();
        }
#pragma unroll
        for (int r2 = 0; r2 < 4; ++r2)
            kF[((size_t)(b * 64 + hk * 2 + (w >> 1)) * 64
                + ((w & 1) * 2 + (l15 >> 3)) * 16 + lg * 4 + r2) * 8 + (l15 & 7)]
                = f2bf(acck[r2]);
#pragma unroll
        for (int mt = 0; mt < 2; ++mt)
#pragma unroll
            for (int ot = 0; ot < 4; ++ot)
#pragma unroll
                for (int r2 = 0; r2 < 4; ++r2)
                    voF[(((size_t)(b * 32 + hk) * 16 + w * 4 + ot) * 64
                         + (mt * 2 + (l15 >> 3)) * 16 + lg * 4 + r2) * 8 + (l15 & 7)]
                        = f2bf(accv[mt][ot][r2]);
    }
}

// ==== fused flash attention (MFMA) + epilogue ===============================
// 4 waves (256 thr), 64 q-rows, FULL m per wave (32 iters), grid 512 (2/CU).
// Wave w: QK n-tile w, PV o-slice w*64. 2-DEEP VO prefetch across lgkm-only
// barriers; branch-free steady state (iter 31 peeled, clamped prefetch idx).
__launch_bounds__(256, 2)
__global__ void attn_kernel(const u16* __restrict__ qF, const u16* __restrict__ kF,
                            const u16* __restrict__ voF, const float* __restrict__ x,
                            const float* __restrict__ gamma, float* __restrict__ out) {
    __shared__ __align__(16) u16   p_lds[2][64 * 40];   // [buf][n][m] 10 KB
    __shared__ __align__(16) float rs_lds[64];

    const int t   = threadIdx.x;
    const int w   = t >> 6, l = t & 63;
    const int l15 = l & 15, lg = l >> 4;
    const int b   = blockIdx.x & 7;              // batch -> XCD pin
    const int n0  = (blockIdx.x >> 3) << 6;      // 64-row tile

    bf16x8 qf = *(const bf16x8*)(qF + ((size_t)(b * 256 + (n0 >> 4) + w) * 64 + l) * 8);
    const u16* kfp = kF  + ((size_t)(b * 64) * 64 + l) * 8;                 // + m16*512
    const u16* vbl = voF + ((size_t)((b * 32) * 16 + w * 4) * 64 + l) * 8;  // + i*8192 + of*512

    u16*       pwp = &p_lds[0][(w * 16 + l15) * 40 + lg * 4];
    const u16* prp = &p_lds[0][l15 * 40 + lg * 8];

    f32x4 acc[4][4];
    const f32x4 fz = {0.f, 0.f, 0.f, 0.f};
#pragma unroll
    for (int j = 0; j < 4; ++j)
#pragma unroll
        for (int of = 0; of < 4; ++of) acc[j][of] = fz;
    float rs = 0.f;

    // ---- prologue: P(0) -> buf0; K frags for QK(1); VO(0) + VO(1) issued ---
    bf16x8 kf0 = *(const bf16x8*)(kfp);
    bf16x8 kf1 = *(const bf16x8*)(kfp + 512);
    {
        f32x4 c0 = MFMA16(kf0, qf, fz, 0, 0, 0);
        f32x4 c1 = MFMA16(kf1, qf, fz, 0, 0, 0);
        float e0 = __builtin_amdgcn_exp2f(c0[0]);
        float e1 = __builtin_amdgcn_exp2f(c0[1]);
        float e2 = __builtin_amdgcn_exp2f(c0[2]);
        float e3 = __builtin_amdgcn_exp2f(c0[3]);
        float e4 = __builtin_amdgcn_exp2f(c1[0]);
        float e5 = __builtin_amdgcn_exp2f(c1[1]);
        float e6 = __builtin_amdgcn_exp2f(c1[2]);
        float e7 = __builtin_amdgcn_exp2f(c1[3]);
        rs += (e0 + e1 + e2 + e3) + (e4 + e5 + e6 + e7);
        uint2 pw0, pw1;
        pw0.x = cvt_pk_bf16(e0, e1);
        pw0.y = cvt_pk_bf16(e2, e3);
        pw1.x = cvt_pk_bf16(e4, e5);
        pw1.y = cvt_pk_bf16(e6, e7);
        *(uint2*)pwp        = pw0;
        *(uint2*)(pwp + 16) = pw1;
    }
    kf0 = *(const bf16x8*)(kfp + 2 * 512);
    kf1 = *(const bf16x8*)(kfp + 3 * 512);
    bf16x8 vof0[4], vof1[4];
#pragma unroll
    for (int of = 0; of < 4; ++of)
        vof0[of] = *(const bf16x8*)(vbl + of * 512);
#pragma unroll
    for (int of = 0; of < 4; ++of)
        vof1[of] = *(const bf16x8*)(vbl + 8192 + of * 512);
    asm volatile("s_waitcnt lgkmcnt(0)" ::: "memory");
    __builtin_amdgcn_s_barrier();

    // ---- steady state: i = 0..30, fully unconditional body ------------------
#pragma unroll 2
    for (int i = 0; i < 31; ++i) {
        const int buf = i & 1;
        // VO(i+2) prefetch (clamped; ~2 iters of latency cover)
        const int ip2 = (i + 2 > 31) ? 31 : (i + 2);
        bf16x8 vof2[4];
#pragma unroll
        for (int of = 0; of < 4; ++of)
            vof2[of] = *(const bf16x8*)(vbl + (size_t)ip2 * 8192 + of * 512);
        // QK(i+1) + P-write into buf^1
        {
            f32x4 c0 = MFMA16(kf0, qf, fz, 0, 0, 0);
            f32x4 c1 = MFMA16(kf1, qf, fz, 0, 0, 0);
            const int k0i = (2 * i + 4 > 62) ? 62 : (2 * i + 4);   // clamped K prefetch
            kf0 = *(const bf16x8*)(kfp + (size_t)k0i * 512);
            kf1 = *(const bf16x8*)(kfp + (size_t)(k0i + 1) * 512);
            float e0 = __builtin_amdgcn_exp2f(c0[0]);
            float e1 = __builtin_amdgcn_exp2f(c0[1]);
            float e2 = __builtin_amdgcn_exp2f(c0[2]);
            float e3 = __builtin_amdgcn_exp2f(c0[3]);
            float e4 = __builtin_amdgcn_exp2f(c1[0]);
            float e5 = __builtin_amdgcn_exp2f(c1[1]);
            float e6 = __builtin_amdgcn_exp2f(c1[2]);
            float e7 = __builtin_amdgcn_exp2f(c1[3]);
            rs += (e0 + e1 + e2 + e3) + (e4 + e5 + e6 + e7);
            uint2 pw0, pw1;
            pw0.x = cvt_pk_bf16(e0, e1);
            pw0.y = cvt_pk_bf16(e2, e3);
            pw1.x = cvt_pk_bf16(e4, e5);
            pw1.y = cvt_pk_bf16(e6, e7);
            u16* pw = pwp + (buf ^ 1) * 2560;
            *(uint2*)pw        = pw0;
            *(uint2*)(pw + 16) = pw1;
        }
        // PV(i) with vof0 (loaded 2 iters ago — resident)
        const u16* pr = prp + buf * 2560;
        __builtin_amdgcn_s_setprio(1);
#pragma unroll
        for (int j = 0; j < 4; ++j) {
            bf16x8 pa = *(const bf16x8*)(pr + j * 640);
#pragma unroll
            for (int of = 0; of < 4; ++of)
                acc[j][of] = MFMA16(pa, vof0[of], acc[j][of], 0, 0, 0);
        }
        __builtin_amdgcn_s_setprio(0);
        // single barrier: LDS drain only; global loads stay in flight
        asm volatile("s_waitcnt lgkmcnt(0)" ::: "memory");
        __builtin_amdgcn_s_barrier();
        // rotate pipelines
#pragma unroll
        for (int of = 0; of < 4; ++of) { vof0[of] = vof1[of]; vof1[of] = vof2[of]; }
    }

    // ---- tail: PV(31) from buf1 ---------------------------------------------
    {
        const u16* pr = prp + 2560;
#pragma unroll
        for (int j = 0; j < 4; ++j) {
            bf16x8 pa = *(const bf16x8*)(pr + j * 640);
#pragma unroll
            for (int of = 0; of < 4; ++of)
                acc[j][of] = MFMA16(pa, vof0[of], acc[j][of], 0, 0, 0);
        }
    }

    // ---- row sums (full m per wave) -----------------------------------------
    rs += __shfl_xor(rs, 16);
    rs += __shfl_xor(rs, 32);
    if (l < 16) rs_lds[w * 16 + l] = rs;
    __syncthreads();

    // ---- epilogue (all 4 waves): out[b][o][n] = x + g * O / rs --------------
    float g = gamma[0];
#pragma unroll
    for (int j = 0; j < 4; ++j) {
        int rbase = j * 16 + lg * 4;
        float fa0 = g / rs_lds[rbase + 0];
        float fa1 = g / rs_lds[rbase + 1];
        float fa2 = g / rs_lds[rbase + 2];
        float fa3 = g / rs_lds[rbase + 3];
#pragma unroll
        for (int of = 0; of < 4; ++of) {
            size_t base = ((size_t)(b * CC + w * 64 + of * 16 + l15)) * NN
                        + n0 + j * 16 + lg * 4;
            float4 xv = *(const float4*)(x + base);
            float4 ov;
            ov.x = xv.x + acc[j][of][0] * fa0;
            ov.y = xv.y + acc[j][of][1] * fa1;
            ov.z = xv.z + acc[j][of][2] * fa2;
            ov.w = xv.w + acc[j][of][3] * fa3;
            *(float4*)(out + base) = ov;
        }
    }
}

extern "C" void kernel_launch(void* const* d_in, const int* in_sizes, int n_in,
                              void* d_out, int out_size, void* d_ws, size_t ws_size,
                              hipStream_t stream) {
    const float* x     = (const float*)d_in[0];
    const float* wq    = (const float*)d_in[1];
    const float* wk    = (const float*)d_in[2];
    const float* wv    = (const float*)d_in[3];
    const float* wo    = (const float*)d_in[4];
    const float* gamma = (const float*)d_in[5];
    float* out = (float*)d_out;
    float* ws  = (float*)d_ws;

    u16* wvob = (u16*)(ws + OFF_WVO);
    u16* wqb  = (u16*)(ws + OFF_WQB);
    u16* wkb  = (u16*)(ws + OFF_WKB);
    u16* qF   = (u16*)(ws + OFF_QF);
    u16* kF   = (u16*)(ws + OFF_KF);
    u16* voF  = (u16*)(ws + OFF_VOF);

    wprep_kernel<<<dim3(256), dim3(1024), 0, stream>>>(wq, wk, wv, wo, wqb, wkb, wvob);
    proj_kernel <<<dim3(512), dim3(256),  0, stream>>>(x, wqb, wkb, wvob, qF, kF, voF);
    attn_kernel <<<dim3(512), dim3(256),  0, stream>>>(qF, kF, voF, x, gamma, out);
}